// Round 9
// baseline (395.190 us; speedup 1.0000x reference)
//
#include <hip/hip_runtime.h>

#define NEG 0.2f
#define EPSV 1e-16f
#define BSH 6  // 64 nodes per bucket

typedef _Float16 h2 __attribute__((ext_vector_type(2)));
typedef _Float16 h4 __attribute__((ext_vector_type(4)));
typedef _Float16 h8 __attribute__((ext_vector_type(8)));

__device__ __forceinline__ float lrelu(float x) { return x > 0.f ? x : NEG * x; }

__device__ __forceinline__ float dot2f(h2 a, h2 b, float c) {
#if __has_builtin(__builtin_amdgcn_fdot2)
  return __builtin_amdgcn_fdot2(a, b, c, false);
#else
  return c + (float)a[0] * (float)b[0] + (float)a[1] * (float)b[1];
#endif
}

// ---------------- CSR build ----------------
__global__ void k_zero(int* __restrict__ p, int n) {
  int t = blockIdx.x * 256 + threadIdx.x;
  if (t < n) p[t] = 0;
}
__global__ void k_hist(const int* __restrict__ dst, int* __restrict__ cnt, int E) {
  int t = blockIdx.x * 256 + threadIdx.x;
  if (t < E) atomicAdd(&cnt[dst[t]], 1);
}
__global__ __launch_bounds__(1024) void k_scan1(const int* __restrict__ cnt,
                                                int* __restrict__ row_ptr,
                                                int* __restrict__ bsum, int N) {
  __shared__ int sh[1024];
  int t = blockIdx.x * 1024 + threadIdx.x;
  int v = (t < N) ? cnt[t] : 0;
  sh[threadIdx.x] = v;
  __syncthreads();
  for (int off = 1; off < 1024; off <<= 1) {
    int add = (threadIdx.x >= off) ? sh[threadIdx.x - off] : 0;
    __syncthreads();
    sh[threadIdx.x] += add;
    __syncthreads();
  }
  if (t < N) row_ptr[t] = sh[threadIdx.x] - v;
  if (threadIdx.x == 1023) bsum[blockIdx.x] = sh[1023];
}
__global__ __launch_bounds__(64) void k_scan2(int* __restrict__ bsum,
                                              int* __restrict__ row_ptr, int nb, int N) {
  int tid = threadIdx.x;
  int v = (tid < nb) ? bsum[tid] : 0;
  int inc = v;
#pragma unroll
  for (int off = 1; off < 64; off <<= 1) {
    int u = __shfl_up(inc, off);
    if (tid >= off) inc += u;
  }
  if (tid < nb) bsum[tid] = inc - v;
  if (tid == 63) row_ptr[N] = inc;
}
// add block offsets; produce per-node cursor and per-bucket cursor
__global__ void k_scan3(const int* __restrict__ bsum, int* __restrict__ row_ptr,
                        int* __restrict__ cursor, int* __restrict__ bcur, int N) {
  int t = blockIdx.x * 256 + threadIdx.x;
  if (t < N) {
    int v = row_ptr[t] + bsum[t >> 10];
    row_ptr[t] = v;
    cursor[t] = v;
    if ((t & 63) == 0) bcur[t >> BSH] = v;
  }
}
// phase 1 scatter: bin edges by dst bucket; pack src(low 26b) | dstlocal(top 6b)
__global__ void k_bin(const int* __restrict__ src, const int* __restrict__ dst,
                      int* __restrict__ bcur, unsigned* __restrict__ binned, int E) {
  int t = blockIdx.x * 256 + threadIdx.x;
  if (t >= E) return;
  int d = dst[t];
  int pos = atomicAdd(&bcur[d >> BSH], 1);
  binned[pos] = (unsigned)src[t] | ((unsigned)(d & 63) << 26);
}
// phase 2: per-bucket scatter into final CSR slots (bucket slice is L2-local)
__global__ __launch_bounds__(256) void k_unbin(const int* __restrict__ row_ptr,
                                               const unsigned* __restrict__ binned,
                                               int* __restrict__ cursor,
                                               int* __restrict__ csr_src, int N) {
  const int n0 = blockIdx.x << BSH;
  const int n1 = min(n0 + 64, N);
  const int start = row_ptr[n0], end = row_ptr[n1];
  for (int t = start + (int)threadIdx.x; t < end; t += 256) {
    unsigned v = binned[t];
    int d = n0 + (int)(v >> 26);
    int pos = atomicAdd(&cursor[d], 1);
    csr_src[pos] = (int)(v & 0x03FFFFFFu);
  }
}

// ------- GEMM via v_dot2_f32_f16: Hout[N,M] (fp16) = X[N,128] (fp32) @ W[128,M] -------
template <int M, int R>
__global__ __launch_bounds__(256) void k_gemm_dot(const float* __restrict__ X,
                                                  const float* __restrict__ W,
                                                  _Float16* __restrict__ Hout, int N) {
  constexpr int K = 128;
  constexpr int XS = 136;
  __shared__ _Float16 wt[M * K];
  __shared__ _Float16 xs[R * XS];
  const int tid = threadIdx.x;
  const long row0 = (long)blockIdx.x * R;
  const int nrow = (int)min((long)R, (long)N - row0);

  for (int idx = tid; idx < (K / 4) * M; idx += 256) {
    int c = idx % M;
    int k0 = (idx / M) * 4;
    h4 o;
    o[0] = (_Float16)W[(k0 + 0) * M + c];
    o[1] = (_Float16)W[(k0 + 1) * M + c];
    o[2] = (_Float16)W[(k0 + 2) * M + c];
    o[3] = (_Float16)W[(k0 + 3) * M + c];
    *(h4*)&wt[c * K + (k0 ^ (4 * (c & 31)))] = o;
  }
  for (int idx = tid; idx < R * (K / 4); idx += 256) {
    int r = idx >> 5;
    int iw = idx & 31;
    float4 v = make_float4(0.f, 0.f, 0.f, 0.f);
    if (r < nrow) v = *(const float4*)&X[(row0 + r) * K + iw * 4];
    h4 o;
    o[0] = (_Float16)v.x;
    o[1] = (_Float16)v.y;
    o[2] = (_Float16)v.z;
    o[3] = (_Float16)v.w;
    *(h4*)&xs[r * XS + iw * 4] = o;
  }
  __syncthreads();

  constexpr int CG = M / 4;
  constexpr int RT = (R * CG) / 256;
  const int tq = tid % CG;
  const int r0 = (tid / CG) * RT;
  int wbase[4], wmask[4];
#pragma unroll
  for (int q = 0; q < 4; q++) {
    int c = tq + CG * q;
    wbase[q] = c * K;
    wmask[q] = 4 * (c & 31);
  }
  float acc[RT][4];
#pragma unroll
  for (int r = 0; r < RT; r++)
#pragma unroll
    for (int q = 0; q < 4; q++) acc[r][q] = 0.f;

  for (int k = 0; k < K; k += 8) {
    h4 wlo[4], whi[4];
#pragma unroll
    for (int q = 0; q < 4; q++) {
      wlo[q] = *(h4*)&wt[wbase[q] + ((k + 0) ^ wmask[q])];
      whi[q] = *(h4*)&wt[wbase[q] + ((k + 4) ^ wmask[q])];
    }
#pragma unroll
    for (int r = 0; r < RT; r++) {
      h8 xv = *(h8*)&xs[(r0 + r) * XS + k];
      h2 x0 = __builtin_shufflevector(xv, xv, 0, 1);
      h2 x1 = __builtin_shufflevector(xv, xv, 2, 3);
      h2 x2 = __builtin_shufflevector(xv, xv, 4, 5);
      h2 x3 = __builtin_shufflevector(xv, xv, 6, 7);
#pragma unroll
      for (int q = 0; q < 4; q++) {
        h2 w0 = __builtin_shufflevector(wlo[q], wlo[q], 0, 1);
        h2 w1 = __builtin_shufflevector(wlo[q], wlo[q], 2, 3);
        h2 w2 = __builtin_shufflevector(whi[q], whi[q], 0, 1);
        h2 w3 = __builtin_shufflevector(whi[q], whi[q], 2, 3);
        acc[r][q] = dot2f(x0, w0, acc[r][q]);
        acc[r][q] = dot2f(x1, w1, acc[r][q]);
        acc[r][q] = dot2f(x2, w2, acc[r][q]);
        acc[r][q] = dot2f(x3, w3, acc[r][q]);
      }
    }
  }
#pragma unroll
  for (int r = 0; r < RT; r++) {
    if (r0 + r < nrow) {
#pragma unroll
      for (int q = 0; q < 4; q++)
        Hout[(row0 + r0 + r) * M + tq + CG * q] = (_Float16)acc[r][q];
    }
  }
}

// ---------------- attention dots (fp16 H) ----------------
template <int H, int C>
__global__ void k_att(const _Float16* __restrict__ Hf, const float* __restrict__ atts,
                      const float* __restrict__ attd, float* __restrict__ as_,
                      float* __restrict__ ad_, int N) {
  int t = blockIdx.x * 256 + threadIdx.x;
  if (t >= N * H) return;
  int n = t / H, h = t % H;
  const _Float16* hp = Hf + (long)n * (H * C) + h * C;
  const float* sp = atts + h * C;
  const float* dp = attd + h * C;
  float s = 0.f, d = 0.f;
#pragma unroll
  for (int c = 0; c < C; c += 8) {
    h8 hv = *(const h8*)&hp[c];
#pragma unroll
    for (int q = 0; q < 8; q++) {
      float v = (float)hv[q];
      s += v * sp[c + q];
      d += v * dp[c + q];
    }
  }
  as_[t] = s;
  ad_[t] = d;
}

// ------- single-pass per-node softmax+aggregate, layer 1 (H=8,C=16) -------
__global__ __launch_bounds__(256) void k_node1(const int* __restrict__ row_ptr,
                                               const int* __restrict__ csr_src,
                                               const _Float16* __restrict__ Hf,
                                               const float* __restrict__ as_,
                                               const float* __restrict__ ad_,
                                               const float* __restrict__ bias,
                                               float* __restrict__ out, int N) {
  const int wid = threadIdx.x >> 6, lane = threadIdx.x & 63;
  const int i = blockIdx.x * 4 + wid;
  if (i >= N) return;
  const int beg = row_ptr[i];
  const int deg = row_ptr[i + 1] - beg;
  const int sub = lane >> 4, ln = lane & 15;
  const int f0 = ln * 8, hf = ln >> 1;

  const float adh = ad_[i * 8 + hf];
  const float pself = __expf(lrelu(as_[i * 8 + hf] + adh));
  float acc[8] = {0.f, 0.f, 0.f, 0.f, 0.f, 0.f, 0.f, 0.f};
  float sp = 0.f;

  int e = sub;
  for (; e + 4 < deg; e += 8) {
    int j0 = csr_src[beg + e], j1 = csr_src[beg + e + 4];
    float p0 = __expf(lrelu(as_[j0 * 8 + hf] + adh));
    float p1 = __expf(lrelu(as_[j1 * 8 + hf] + adh));
    h8 v0 = *(const h8*)&Hf[(long)j0 * 128 + f0];
    h8 v1 = *(const h8*)&Hf[(long)j1 * 128 + f0];
    sp += p0 + p1;
#pragma unroll
    for (int c = 0; c < 8; c++) acc[c] += p0 * (float)v0[c] + p1 * (float)v1[c];
  }
  for (; e < deg; e += 4) {
    int j = csr_src[beg + e];
    float p = __expf(lrelu(as_[j * 8 + hf] + adh));
    h8 v = *(const h8*)&Hf[(long)j * 128 + f0];
    sp += p;
#pragma unroll
    for (int c = 0; c < 8; c++) acc[c] += p * (float)v[c];
  }
  if (sub == 0) {
    h8 hv = *(const h8*)&Hf[(long)i * 128 + f0];
#pragma unroll
    for (int c = 0; c < 8; c++) acc[c] += pself * (float)hv[c];
  }
  sp += __shfl_xor(sp, 16);
  sp += __shfl_xor(sp, 32);
  const float rd = 1.f / (sp + pself + EPSV);
#pragma unroll
  for (int c = 0; c < 8; c++) {
    acc[c] += __shfl_xor(acc[c], 16);
    acc[c] += __shfl_xor(acc[c], 32);
  }
  if (sub == 0) {
    float4 b0 = *(const float4*)&bias[f0];
    float4 b1 = *(const float4*)&bias[f0 + 4];
    float4 o0, o1;
    o0.x = fmaxf(acc[0] * rd + b0.x, 0.f);
    o0.y = fmaxf(acc[1] * rd + b0.y, 0.f);
    o0.z = fmaxf(acc[2] * rd + b0.z, 0.f);
    o0.w = fmaxf(acc[3] * rd + b0.w, 0.f);
    o1.x = fmaxf(acc[4] * rd + b1.x, 0.f);
    o1.y = fmaxf(acc[5] * rd + b1.y, 0.f);
    o1.z = fmaxf(acc[6] * rd + b1.z, 0.f);
    o1.w = fmaxf(acc[7] * rd + b1.w, 0.f);
    *(float4*)&out[(long)i * 128 + f0] = o0;
    *(float4*)&out[(long)i * 128 + f0 + 4] = o1;
  }
}

// ------- single-pass per-node softmax+aggregate, layer 2 (H=1,C=64) -------
__global__ __launch_bounds__(256) void k_node2(const int* __restrict__ row_ptr,
                                               const int* __restrict__ csr_src,
                                               const _Float16* __restrict__ Hf,
                                               const float* __restrict__ as_,
                                               const float* __restrict__ ad_,
                                               const float* __restrict__ bias,
                                               float* __restrict__ out, int N) {
  const int wid = threadIdx.x >> 6, lane = threadIdx.x & 63;
  const int i = blockIdx.x * 4 + wid;
  if (i >= N) return;
  const int beg = row_ptr[i];
  const int deg = row_ptr[i + 1] - beg;
  const int sub = lane >> 3, ln = lane & 7;
  const int f0 = ln * 8;

  const float adi = ad_[i];
  const float pself = __expf(lrelu(as_[i] + adi));
  float acc[8] = {0.f, 0.f, 0.f, 0.f, 0.f, 0.f, 0.f, 0.f};
  float sp = 0.f;

  int e = sub;
  for (; e + 8 < deg; e += 16) {
    int j0 = csr_src[beg + e], j1 = csr_src[beg + e + 8];
    float p0 = __expf(lrelu(as_[j0] + adi));
    float p1 = __expf(lrelu(as_[j1] + adi));
    h8 v0 = *(const h8*)&Hf[(long)j0 * 64 + f0];
    h8 v1 = *(const h8*)&Hf[(long)j1 * 64 + f0];
    sp += p0 + p1;
#pragma unroll
    for (int c = 0; c < 8; c++) acc[c] += p0 * (float)v0[c] + p1 * (float)v1[c];
  }
  for (; e < deg; e += 8) {
    int j = csr_src[beg + e];
    float p = __expf(lrelu(as_[j] + adi));
    h8 v = *(const h8*)&Hf[(long)j * 64 + f0];
    sp += p;
#pragma unroll
    for (int c = 0; c < 8; c++) acc[c] += p * (float)v[c];
  }
  if (sub == 0) {
    h8 hv = *(const h8*)&Hf[(long)i * 64 + f0];
#pragma unroll
    for (int c = 0; c < 8; c++) acc[c] += pself * (float)hv[c];
  }
  sp += __shfl_xor(sp, 8);
  sp += __shfl_xor(sp, 16);
  sp += __shfl_xor(sp, 32);
  const float rd = 1.f / (sp + pself + EPSV);
#pragma unroll
  for (int c = 0; c < 8; c++) {
    acc[c] += __shfl_xor(acc[c], 8);
    acc[c] += __shfl_xor(acc[c], 16);
    acc[c] += __shfl_xor(acc[c], 32);
  }
  if (sub == 0) {
    float4 b0 = *(const float4*)&bias[f0];
    float4 b1 = *(const float4*)&bias[f0 + 4];
    float4 o0, o1;
    o0.x = acc[0] * rd + b0.x;
    o0.y = acc[1] * rd + b0.y;
    o0.z = acc[2] * rd + b0.z;
    o0.w = acc[3] * rd + b0.w;
    o1.x = acc[4] * rd + b1.x;
    o1.y = acc[5] * rd + b1.y;
    o1.z = acc[6] * rd + b1.z;
    o1.w = acc[7] * rd + b1.w;
    *(float4*)&out[(long)i * 64 + f0] = o0;
    *(float4*)&out[(long)i * 64 + f0 + 4] = o1;
  }
}

extern "C" void kernel_launch(void* const* d_in, const int* in_sizes, int n_in,
                              void* d_out, int out_size, void* d_ws, size_t ws_size,
                              hipStream_t stream) {
  const float* x = (const float*)d_in[0];
  const int* ei = (const int*)d_in[1];
  const float* W1 = (const float*)d_in[2];
  const float* s1 = (const float*)d_in[3];
  const float* dd1 = (const float*)d_in[4];
  const float* b1 = (const float*)d_in[5];
  const float* W2 = (const float*)d_in[6];
  const float* s2 = (const float*)d_in[7];
  const float* dd2 = (const float*)d_in[8];
  const float* b2 = (const float*)d_in[9];
  const int N = in_sizes[0] / 128;
  const int E = in_sizes[1] / 2;
  const int* src = ei;
  const int* dst = ei + E;
  const int nbuckets = (N + 63) >> BSH;

  // ws: Hh[N*128 h] | as[N*8] | ad[N*8] | X2[N*128] | row_ptr[N+1] | csr_src[E] |
  //     bsum[64] | bcur[nbuckets] | binned[E]
  char* wsp = (char*)d_ws;
  _Float16* Hh = (_Float16*)wsp;
  float* as1 = (float*)(wsp + (size_t)N * 128 * sizeof(_Float16));
  float* ad1 = as1 + (size_t)N * 8;
  float* X2 = ad1 + (size_t)N * 8;
  int* row_ptr = (int*)(X2 + (size_t)N * 128);
  int* csr_src = row_ptr + (N + 1);
  int* bsum = csr_src + E;
  int* bcur = bsum + 64;
  unsigned* binned = (unsigned*)(bcur + nbuckets);
  int* cursor = (int*)as1;  // alias: dead before k_att writes as1
  float* out = (float*)d_out;

  dim3 B(256);
  auto nb = [](long n) { return dim3((unsigned)((n + 255) / 256)); };
  const int nblk = (N + 1023) / 1024;

  // CSR build (by destination), binned two-phase scatter
  k_zero<<<nb(N), B, 0, stream>>>(cursor, N);
  k_hist<<<nb(E), B, 0, stream>>>(dst, cursor, E);
  k_scan1<<<dim3(nblk), dim3(1024), 0, stream>>>(cursor, row_ptr, bsum, N);
  k_scan2<<<dim3(1), dim3(64), 0, stream>>>(bsum, row_ptr, nblk, N);
  k_scan3<<<nb(N), B, 0, stream>>>(bsum, row_ptr, cursor, bcur, N);
  k_bin<<<nb(E), B, 0, stream>>>(src, dst, bcur, binned, E);
  k_unbin<<<dim3(nbuckets), B, 0, stream>>>(row_ptr, binned, cursor, csr_src, N);

  // Layer 1
  k_gemm_dot<128, 64><<<dim3((N + 63) / 64), B, 0, stream>>>(x, W1, Hh, N);
  k_att<8, 16><<<nb((long)N * 8), B, 0, stream>>>(Hh, s1, dd1, as1, ad1, N);
  k_node1<<<dim3((N + 3) / 4), B, 0, stream>>>(row_ptr, csr_src, Hh, as1, ad1, b1, X2, N);

  // Layer 2 (Hh reused: N*64 fp16 fits in the N*128 slot)
  k_gemm_dot<64, 64><<<dim3((N + 63) / 64), B, 0, stream>>>(X2, W2, Hh, N);
  k_att<1, 64><<<nb(N), B, 0, stream>>>(Hh, s2, dd2, as1, ad1, N);
  k_node2<<<dim3((N + 3) / 4), B, 0, stream>>>(row_ptr, csr_src, Hh, as1, ad1, b2, out, N);
}

// Round 10
// 217.149 us; speedup vs baseline: 1.8199x; 1.8199x over previous
//
#include <hip/hip_runtime.h>

#define NEG 0.2f
#define EPSV 1e-16f

typedef _Float16 h2 __attribute__((ext_vector_type(2)));
typedef _Float16 h4 __attribute__((ext_vector_type(4)));
typedef _Float16 h8 __attribute__((ext_vector_type(8)));

__device__ __forceinline__ float lrelu(float x) { return x > 0.f ? x : NEG * x; }

__device__ __forceinline__ float dot2f(h2 a, h2 b, float c) {
#if __has_builtin(__builtin_amdgcn_fdot2)
  return __builtin_amdgcn_fdot2(a, b, c, false);
#else
  return c + (float)a[0] * (float)b[0] + (float)a[1] * (float)b[1];
#endif
}

// ---------------- CSR build ----------------
__global__ void k_zero(int* __restrict__ p, int n) {
  int t = blockIdx.x * 256 + threadIdx.x;
  if (t < n) p[t] = 0;
}
__global__ void k_hist(const int* __restrict__ dst, int* __restrict__ cnt, int E) {
  int t = blockIdx.x * 256 + threadIdx.x;
  if (t < E) atomicAdd(&cnt[dst[t]], 1);
}
__global__ __launch_bounds__(1024) void k_scan1(const int* __restrict__ cnt,
                                                int* __restrict__ row_ptr,
                                                int* __restrict__ bsum, int N) {
  __shared__ int sh[1024];
  int t = blockIdx.x * 1024 + threadIdx.x;
  int v = (t < N) ? cnt[t] : 0;
  sh[threadIdx.x] = v;
  __syncthreads();
  for (int off = 1; off < 1024; off <<= 1) {
    int add = (threadIdx.x >= off) ? sh[threadIdx.x - off] : 0;
    __syncthreads();
    sh[threadIdx.x] += add;
    __syncthreads();
  }
  if (t < N) row_ptr[t] = sh[threadIdx.x] - v;
  if (threadIdx.x == 1023) bsum[blockIdx.x] = sh[1023];
}
__global__ __launch_bounds__(64) void k_scan2(int* __restrict__ bsum,
                                              int* __restrict__ row_ptr, int nb, int N) {
  int tid = threadIdx.x;
  int v = (tid < nb) ? bsum[tid] : 0;
  int inc = v;
#pragma unroll
  for (int off = 1; off < 64; off <<= 1) {
    int u = __shfl_up(inc, off);
    if (tid >= off) inc += u;
  }
  if (tid < nb) bsum[tid] = inc - v;
  if (tid == 63) row_ptr[N] = inc;
}
__global__ void k_scan3(const int* __restrict__ bsum, int* __restrict__ row_ptr,
                        int* __restrict__ cursor, int N) {
  int t = blockIdx.x * 256 + threadIdx.x;
  if (t < N) {
    int v = row_ptr[t] + bsum[t >> 10];
    row_ptr[t] = v;
    cursor[t] = v;
  }
}
__global__ void k_scatter(const int* __restrict__ src, const int* __restrict__ dst,
                          int* __restrict__ cursor, unsigned short* __restrict__ csr_src,
                          int E) {
  int t = blockIdx.x * 256 + threadIdx.x;
  if (t >= E) return;
  int i = dst[t];
  int pos = atomicAdd(&cursor[i], 1);
  csr_src[pos] = (unsigned short)src[t];
}

// ------- GEMM via v_dot2_f32_f16: Hout[N,M] (fp16) = X[N,128] (fp32) @ W[128,M] -------
template <int M, int R>
__global__ __launch_bounds__(256) void k_gemm_dot(const float* __restrict__ X,
                                                  const float* __restrict__ W,
                                                  _Float16* __restrict__ Hout, int N) {
  constexpr int K = 128;
  constexpr int XS = 136;
  __shared__ _Float16 wt[M * K];
  __shared__ _Float16 xs[R * XS];
  const int tid = threadIdx.x;
  const long row0 = (long)blockIdx.x * R;
  const int nrow = (int)min((long)R, (long)N - row0);

  for (int idx = tid; idx < (K / 4) * M; idx += 256) {
    int c = idx % M;
    int k0 = (idx / M) * 4;
    h4 o;
    o[0] = (_Float16)W[(k0 + 0) * M + c];
    o[1] = (_Float16)W[(k0 + 1) * M + c];
    o[2] = (_Float16)W[(k0 + 2) * M + c];
    o[3] = (_Float16)W[(k0 + 3) * M + c];
    *(h4*)&wt[c * K + (k0 ^ (4 * (c & 31)))] = o;
  }
  for (int idx = tid; idx < R * (K / 4); idx += 256) {
    int r = idx >> 5;
    int iw = idx & 31;
    float4 v = make_float4(0.f, 0.f, 0.f, 0.f);
    if (r < nrow) v = *(const float4*)&X[(row0 + r) * K + iw * 4];
    h4 o;
    o[0] = (_Float16)v.x;
    o[1] = (_Float16)v.y;
    o[2] = (_Float16)v.z;
    o[3] = (_Float16)v.w;
    *(h4*)&xs[r * XS + iw * 4] = o;
  }
  __syncthreads();

  constexpr int CG = M / 4;
  constexpr int RT = (R * CG) / 256;
  const int tq = tid % CG;
  const int r0 = (tid / CG) * RT;
  int wbase[4], wmask[4];
#pragma unroll
  for (int q = 0; q < 4; q++) {
    int c = tq + CG * q;
    wbase[q] = c * K;
    wmask[q] = 4 * (c & 31);
  }
  float acc[RT][4];
#pragma unroll
  for (int r = 0; r < RT; r++)
#pragma unroll
    for (int q = 0; q < 4; q++) acc[r][q] = 0.f;

  for (int k = 0; k < K; k += 8) {
    h4 wlo[4], whi[4];
#pragma unroll
    for (int q = 0; q < 4; q++) {
      wlo[q] = *(h4*)&wt[wbase[q] + ((k + 0) ^ wmask[q])];
      whi[q] = *(h4*)&wt[wbase[q] + ((k + 4) ^ wmask[q])];
    }
#pragma unroll
    for (int r = 0; r < RT; r++) {
      h8 xv = *(h8*)&xs[(r0 + r) * XS + k];
      h2 x0 = __builtin_shufflevector(xv, xv, 0, 1);
      h2 x1 = __builtin_shufflevector(xv, xv, 2, 3);
      h2 x2 = __builtin_shufflevector(xv, xv, 4, 5);
      h2 x3 = __builtin_shufflevector(xv, xv, 6, 7);
#pragma unroll
      for (int q = 0; q < 4; q++) {
        h2 w0 = __builtin_shufflevector(wlo[q], wlo[q], 0, 1);
        h2 w1 = __builtin_shufflevector(wlo[q], wlo[q], 2, 3);
        h2 w2 = __builtin_shufflevector(whi[q], whi[q], 0, 1);
        h2 w3 = __builtin_shufflevector(whi[q], whi[q], 2, 3);
        acc[r][q] = dot2f(x0, w0, acc[r][q]);
        acc[r][q] = dot2f(x1, w1, acc[r][q]);
        acc[r][q] = dot2f(x2, w2, acc[r][q]);
        acc[r][q] = dot2f(x3, w3, acc[r][q]);
      }
    }
  }
#pragma unroll
  for (int r = 0; r < RT; r++) {
    if (r0 + r < nrow) {
#pragma unroll
      for (int q = 0; q < 4; q++)
        Hout[(row0 + r0 + r) * M + tq + CG * q] = (_Float16)acc[r][q];
    }
  }
}

// ---------------- attention dots (fp16 H) ----------------
template <int H, int C>
__global__ void k_att(const _Float16* __restrict__ Hf, const float* __restrict__ atts,
                      const float* __restrict__ attd, float* __restrict__ as_,
                      float* __restrict__ ad_, int N) {
  int t = blockIdx.x * 256 + threadIdx.x;
  if (t >= N * H) return;
  int n = t / H, h = t % H;
  const _Float16* hp = Hf + (long)n * (H * C) + h * C;
  const float* sp = atts + h * C;
  const float* dp = attd + h * C;
  float s = 0.f, d = 0.f;
#pragma unroll
  for (int c = 0; c < C; c += 8) {
    h8 hv = *(const h8*)&hp[c];
#pragma unroll
    for (int q = 0; q < 8; q++) {
      float v = (float)hv[q];
      s += v * sp[c + q];
      d += v * dp[c + q];
    }
  }
  as_[t] = s;
  ad_[t] = d;
}

// ------- single-pass per-node softmax+aggregate, layer 1 (H=8,C=16) -------
__global__ __launch_bounds__(256) void k_node1(const int* __restrict__ row_ptr,
                                               const unsigned short* __restrict__ csr_src,
                                               const _Float16* __restrict__ Hf,
                                               const float* __restrict__ as_,
                                               const float* __restrict__ ad_,
                                               const float* __restrict__ bias,
                                               float* __restrict__ out, int N) {
  const int wid = threadIdx.x >> 6, lane = threadIdx.x & 63;
  const int i = blockIdx.x * 4 + wid;
  if (i >= N) return;
  const int beg = row_ptr[i];
  const int deg = row_ptr[i + 1] - beg;
  const int sub = lane >> 4, ln = lane & 15;
  const int f0 = ln * 8, hf = ln >> 1;

  const float adh = ad_[i * 8 + hf];
  const float pself = __expf(lrelu(as_[i * 8 + hf] + adh));
  float acc[8] = {0.f, 0.f, 0.f, 0.f, 0.f, 0.f, 0.f, 0.f};
  float sp = 0.f;

  int e = sub;
  for (; e + 4 < deg; e += 8) {
    int j0 = (int)csr_src[beg + e], j1 = (int)csr_src[beg + e + 4];
    float p0 = __expf(lrelu(as_[j0 * 8 + hf] + adh));
    float p1 = __expf(lrelu(as_[j1 * 8 + hf] + adh));
    h8 v0 = *(const h8*)&Hf[(long)j0 * 128 + f0];
    h8 v1 = *(const h8*)&Hf[(long)j1 * 128 + f0];
    sp += p0 + p1;
#pragma unroll
    for (int c = 0; c < 8; c++) acc[c] += p0 * (float)v0[c] + p1 * (float)v1[c];
  }
  for (; e < deg; e += 4) {
    int j = (int)csr_src[beg + e];
    float p = __expf(lrelu(as_[j * 8 + hf] + adh));
    h8 v = *(const h8*)&Hf[(long)j * 128 + f0];
    sp += p;
#pragma unroll
    for (int c = 0; c < 8; c++) acc[c] += p * (float)v[c];
  }
  if (sub == 0) {
    h8 hv = *(const h8*)&Hf[(long)i * 128 + f0];
#pragma unroll
    for (int c = 0; c < 8; c++) acc[c] += pself * (float)hv[c];
  }
  sp += __shfl_xor(sp, 16);
  sp += __shfl_xor(sp, 32);
  const float rd = 1.f / (sp + pself + EPSV);
#pragma unroll
  for (int c = 0; c < 8; c++) {
    acc[c] += __shfl_xor(acc[c], 16);
    acc[c] += __shfl_xor(acc[c], 32);
  }
  if (sub == 0) {
    float4 b0 = *(const float4*)&bias[f0];
    float4 b1 = *(const float4*)&bias[f0 + 4];
    float4 o0, o1;
    o0.x = fmaxf(acc[0] * rd + b0.x, 0.f);
    o0.y = fmaxf(acc[1] * rd + b0.y, 0.f);
    o0.z = fmaxf(acc[2] * rd + b0.z, 0.f);
    o0.w = fmaxf(acc[3] * rd + b0.w, 0.f);
    o1.x = fmaxf(acc[4] * rd + b1.x, 0.f);
    o1.y = fmaxf(acc[5] * rd + b1.y, 0.f);
    o1.z = fmaxf(acc[6] * rd + b1.z, 0.f);
    o1.w = fmaxf(acc[7] * rd + b1.w, 0.f);
    *(float4*)&out[(long)i * 128 + f0] = o0;
    *(float4*)&out[(long)i * 128 + f0 + 4] = o1;
  }
}

// ------- single-pass per-node softmax+aggregate, layer 2 (H=1,C=64) -------
__global__ __launch_bounds__(256) void k_node2(const int* __restrict__ row_ptr,
                                               const unsigned short* __restrict__ csr_src,
                                               const _Float16* __restrict__ Hf,
                                               const float* __restrict__ as_,
                                               const float* __restrict__ ad_,
                                               const float* __restrict__ bias,
                                               float* __restrict__ out, int N) {
  const int wid = threadIdx.x >> 6, lane = threadIdx.x & 63;
  const int i = blockIdx.x * 4 + wid;
  if (i >= N) return;
  const int beg = row_ptr[i];
  const int deg = row_ptr[i + 1] - beg;
  const int sub = lane >> 3, ln = lane & 7;
  const int f0 = ln * 8;

  const float adi = ad_[i];
  const float pself = __expf(lrelu(as_[i] + adi));
  float acc[8] = {0.f, 0.f, 0.f, 0.f, 0.f, 0.f, 0.f, 0.f};
  float sp = 0.f;

  int e = sub;
  for (; e + 8 < deg; e += 16) {
    int j0 = (int)csr_src[beg + e], j1 = (int)csr_src[beg + e + 8];
    float p0 = __expf(lrelu(as_[j0] + adi));
    float p1 = __expf(lrelu(as_[j1] + adi));
    h8 v0 = *(const h8*)&Hf[(long)j0 * 64 + f0];
    h8 v1 = *(const h8*)&Hf[(long)j1 * 64 + f0];
    sp += p0 + p1;
#pragma unroll
    for (int c = 0; c < 8; c++) acc[c] += p0 * (float)v0[c] + p1 * (float)v1[c];
  }
  for (; e < deg; e += 8) {
    int j = (int)csr_src[beg + e];
    float p = __expf(lrelu(as_[j] + adi));
    h8 v = *(const h8*)&Hf[(long)j * 64 + f0];
    sp += p;
#pragma unroll
    for (int c = 0; c < 8; c++) acc[c] += p * (float)v[c];
  }
  if (sub == 0) {
    h8 hv = *(const h8*)&Hf[(long)i * 64 + f0];
#pragma unroll
    for (int c = 0; c < 8; c++) acc[c] += pself * (float)hv[c];
  }
  sp += __shfl_xor(sp, 8);
  sp += __shfl_xor(sp, 16);
  sp += __shfl_xor(sp, 32);
  const float rd = 1.f / (sp + pself + EPSV);
#pragma unroll
  for (int c = 0; c < 8; c++) {
    acc[c] += __shfl_xor(acc[c], 8);
    acc[c] += __shfl_xor(acc[c], 16);
    acc[c] += __shfl_xor(acc[c], 32);
  }
  if (sub == 0) {
    float4 b0 = *(const float4*)&bias[f0];
    float4 b1 = *(const float4*)&bias[f0 + 4];
    float4 o0, o1;
    o0.x = acc[0] * rd + b0.x;
    o0.y = acc[1] * rd + b0.y;
    o0.z = acc[2] * rd + b0.z;
    o0.w = acc[3] * rd + b0.w;
    o1.x = acc[4] * rd + b1.x;
    o1.y = acc[5] * rd + b1.y;
    o1.z = acc[6] * rd + b1.z;
    o1.w = acc[7] * rd + b1.w;
    *(float4*)&out[(long)i * 64 + f0] = o0;
    *(float4*)&out[(long)i * 64 + f0 + 4] = o1;
  }
}

extern "C" void kernel_launch(void* const* d_in, const int* in_sizes, int n_in,
                              void* d_out, int out_size, void* d_ws, size_t ws_size,
                              hipStream_t stream) {
  const float* x = (const float*)d_in[0];
  const int* ei = (const int*)d_in[1];
  const float* W1 = (const float*)d_in[2];
  const float* s1 = (const float*)d_in[3];
  const float* dd1 = (const float*)d_in[4];
  const float* b1 = (const float*)d_in[5];
  const float* W2 = (const float*)d_in[6];
  const float* s2 = (const float*)d_in[7];
  const float* dd2 = (const float*)d_in[8];
  const float* b2 = (const float*)d_in[9];
  const int N = in_sizes[0] / 128;
  const int E = in_sizes[1] / 2;
  const int* src = ei;
  const int* dst = ei + E;

  // ws: Hh[N*128 h] | as[N*8] | ad[N*8] | X2[N*128] | row_ptr[N+1] | csr_u16[E] | bsum[64]
  char* wsp = (char*)d_ws;
  _Float16* Hh = (_Float16*)wsp;
  float* as1 = (float*)(wsp + (size_t)N * 128 * sizeof(_Float16));
  float* ad1 = as1 + (size_t)N * 8;
  float* X2 = ad1 + (size_t)N * 8;
  int* row_ptr = (int*)(X2 + (size_t)N * 128);
  unsigned short* csr_src = (unsigned short*)(row_ptr + (N + 1));
  int* bsum = (int*)(csr_src + E);
  int* cursor = (int*)as1;  // alias: dead before k_att writes as1
  float* out = (float*)d_out;

  dim3 B(256);
  auto nb = [](long n) { return dim3((unsigned)((n + 255) / 256)); };
  const int nblk = (N + 1023) / 1024;

  // CSR build (by destination)
  k_zero<<<nb(N), B, 0, stream>>>(cursor, N);
  k_hist<<<nb(E), B, 0, stream>>>(dst, cursor, E);
  k_scan1<<<dim3(nblk), dim3(1024), 0, stream>>>(cursor, row_ptr, bsum, N);
  k_scan2<<<dim3(1), dim3(64), 0, stream>>>(bsum, row_ptr, nblk, N);
  k_scan3<<<nb(N), B, 0, stream>>>(bsum, row_ptr, cursor, N);
  k_scatter<<<nb(E), B, 0, stream>>>(src, dst, cursor, csr_src, E);

  // Layer 1
  k_gemm_dot<128, 64><<<dim3((N + 63) / 64), B, 0, stream>>>(x, W1, Hh, N);
  k_att<8, 16><<<nb((long)N * 8), B, 0, stream>>>(Hh, s1, dd1, as1, ad1, N);
  k_node1<<<dim3((N + 3) / 4), B, 0, stream>>>(row_ptr, csr_src, Hh, as1, ad1, b1, X2, N);

  // Layer 2 (Hh reused: N*64 fp16 fits in the N*128 slot)
  k_gemm_dot<64, 64><<<dim3((N + 63) / 64), B, 0, stream>>>(X2, W2, Hh, N);
  k_att<1, 64><<<nb(N), B, 0, stream>>>(Hh, s2, dd2, as1, ad1, N);
  k_node2<<<dim3((N + 3) / 4), B, 0, stream>>>(row_ptr, csr_src, Hh, as1, ad1, b2, out, N);
}